// Round 4
// baseline (92.220 us; speedup 1.0000x reference)
//
#include <hip/hip_runtime.h>
#include <cfloat>

#define TPB 256
#define Q 16         // queries per thread (register tile) in the scan kernel
#define CHUNKS 128   // db chunks (parallelism dimension)
#define RBLK 128     // queries per reduce1 block
#define ALPHA 0.5f

// acc = min(acc, |d0|, |d1|) in ONE VALU instruction. Written as inline asm
// because IEEE mode blocks the compiler's own min3+abs fusion, leaving
// v_sub + v_and + v_min (3 VALU/visit) instead of 1.5 VALU/visit.
__device__ __forceinline__ float min3abs(float acc, float d0, float d1) {
    float r;
    asm("v_min3_f32 %0, %1, |%2|, |%3|"
        : "=v"(r) : "v"(acc), "v"(d0), "v"(d1));
    return r;
}

// ---------------------------------------------------------------------------
// Scan core: Q queries per thread, db slice read via wave-uniform (scalar)
// loads (s_load_dwordx8). Per 8 db elems per query: 8 v_sub + 4 v_min3 = 12
// VALU -> 1.5 VALU per element-visit (the floor for this formulation).
// ---------------------------------------------------------------------------
__device__ __forceinline__ void scan_chunk(const float* __restrict__ db,
                                           int start, int end,
                                           const float qv[Q], float acc[Q]) {
    int j = start;
    for (; j + 8 <= end; j += 8) {
        const float v0 = db[j + 0], v1 = db[j + 1];
        const float v2 = db[j + 2], v3 = db[j + 3];
        const float v4 = db[j + 4], v5 = db[j + 5];
        const float v6 = db[j + 6], v7 = db[j + 7];
#pragma unroll
        for (int k = 0; k < Q; ++k) {
            const float q = qv[k];
            float a = acc[k];
            a = min3abs(a, v0 - q, v1 - q);
            a = min3abs(a, v2 - q, v3 - q);
            a = min3abs(a, v4 - q, v5 - q);
            a = min3abs(a, v6 - q, v7 - q);
            acc[k] = a;
        }
    }
    for (; j < end; ++j) {
        const float v = db[j];
#pragma unroll
        for (int k = 0; k < Q; ++k) acc[k] = fminf(acc[k], fabsf(qv[k] - v));
    }
}

// Partial-store: partial[chunk][query]. Always stores (FLT_MAX for empty
// chunks) so reduce1 never reads poisoned ws. No atomics, no init pass.
__global__ __launch_bounds__(TPB) void
chamfer_partial_kernel(const float* __restrict__ x, const float* __restrict__ y,
                       int n, int m, float* __restrict__ partial) {
    const int tid = blockIdx.y * blockDim.x + threadIdx.x;
    const int qbase = tid * Q;
    const int total = n + m;
    if (qbase >= total) return;

    const float* __restrict__ db;
    const float* qsrc;
    int dbn, qoff;
    if (qbase < n) { db = y; dbn = m; qsrc = x; qoff = qbase; }
    else           { db = x; dbn = n; qsrc = y; qoff = qbase - n; }

    float qv[Q];
#pragma unroll
    for (int k = 0; k < Q; ++k) qv[k] = qsrc[qoff + k];

    const int chunk_len = (dbn + CHUNKS - 1) / CHUNKS;
    const int start = blockIdx.x * chunk_len;
    const int end = min(start + chunk_len, dbn);

    float acc[Q];
#pragma unroll
    for (int k = 0; k < Q; ++k) acc[k] = FLT_MAX;
    if (start < end) scan_chunk(db, start, end, qv, acc);

    float* __restrict__ dst = partial + (size_t)blockIdx.x * total + qbase;
#pragma unroll
    for (int k = 0; k < Q; ++k) dst[k] = acc[k];
}

// Reduce 1: one block per RBLK contiguous queries. 256 threads =
// RBLK queries x 2 chunk-halves; lanes read consecutive queries (coalesced).
__global__ __launch_bounds__(TPB) void
chamfer_reduce1(const float* __restrict__ vals, int n, int m,
                double* __restrict__ bsums) {
    const int total = n + m;
    const int lq = threadIdx.x & (RBLK - 1);   // query within block
    const int h = threadIdx.x >> 7;            // chunk half (0/1)
    const int q = blockIdx.x * RBLK + lq;

    float mv = FLT_MAX;
    if (q < total) {
        const int c0 = h * (CHUNKS / 2), c1 = c0 + CHUNKS / 2;
        for (int c = c0; c < c1; ++c)
            mv = fminf(mv, vals[(size_t)c * total + q]);
    }
    __shared__ float half1[RBLK];
    if (h == 1) half1[lq] = mv;
    __syncthreads();

    double sx = 0.0, sy = 0.0;
    if (h == 0 && q < total) {
        const float best = fminf(mv, half1[lq]);
        if (q < n) sx = (double)best; else sy = (double)best;
    }
    for (int off = 32; off > 0; off >>= 1) {
        sx += __shfl_down(sx, off);
        sy += __shfl_down(sy, off);
    }
    __shared__ double wsx[2], wsy[2];
    if (h == 0 && (threadIdx.x & 63) == 0) {
        wsx[threadIdx.x >> 6] = sx;
        wsy[threadIdx.x >> 6] = sy;
    }
    __syncthreads();
    if (threadIdx.x == 0) {
        bsums[2 * blockIdx.x]     = wsx[0] + wsx[1];
        bsums[2 * blockIdx.x + 1] = wsy[0] + wsy[1];
    }
}

// Reduce 2: fold nb block sums -> scalar loss.
__global__ __launch_bounds__(TPB) void
chamfer_reduce2(const double* __restrict__ bsums, int nb,
                int n, int m, float* __restrict__ out) {
    double sx = 0.0, sy = 0.0;
    for (int i = threadIdx.x; i < nb; i += blockDim.x) {
        sx += bsums[2 * i];
        sy += bsums[2 * i + 1];
    }
    for (int off = 32; off > 0; off >>= 1) {
        sx += __shfl_down(sx, off);
        sy += __shfl_down(sy, off);
    }
    __shared__ double lsx[4], lsy[4];
    const int wave = threadIdx.x >> 6;
    if ((threadIdx.x & 63) == 0) { lsx[wave] = sx; lsy[wave] = sy; }
    __syncthreads();
    if (threadIdx.x == 0) {
        double tx = 0.0, ty = 0.0;
        for (int w = 0; w < (int)(blockDim.x >> 6); ++w) { tx += lsx[w]; ty += lsy[w]; }
        const double a = (double)ALPHA;
        out[0] = (float)(a * tx / (double)n + (1.0 - a) * ty / (double)m);
    }
}

extern "C" void kernel_launch(void* const* d_in, const int* in_sizes, int n_in,
                              void* d_out, int out_size, void* d_ws, size_t ws_size,
                              hipStream_t stream) {
    const float* x = (const float*)d_in[0];
    const float* y = (const float*)d_in[1];
    const int n = in_sizes[0];
    const int m = in_sizes[1];
    float* out = (float*)d_out;
    const int total = n + m;

    const int qgroups = (total + Q - 1) / Q;
    const dim3 grid1(CHUNKS, (qgroups + TPB - 1) / TPB);
    const int nb1 = (total + RBLK - 1) / RBLK;

    const size_t partial_bytes = (size_t)CHUNKS * total * sizeof(float);
    const size_t partial_aligned = (partial_bytes + 255) & ~(size_t)255;

    float* partial = (float*)d_ws;
    double* bsums = (double*)((char*)d_ws + partial_aligned);

    chamfer_partial_kernel<<<grid1, TPB, 0, stream>>>(x, y, n, m, partial);
    chamfer_reduce1<<<nb1, TPB, 0, stream>>>(partial, n, m, bsums);
    chamfer_reduce2<<<1, TPB, 0, stream>>>(bsums, nb1, n, m, out);
}

// Round 5
// 84.038 us; speedup vs baseline: 1.0974x; 1.0974x over previous
//
#include <hip/hip_runtime.h>
#include <cfloat>

#define TPB 256
#define Q 8          // queries per thread (register tile)
#define CHUNKS 64    // db chunks (parallelism dimension)
#define RBLK 128     // queries per reduce1 block
#define ALPHA 0.5f

// acc = min(acc, |d0|, |d1|) in ONE VALU instruction (IEEE mode blocks the
// compiler's own min3+abs fusion).
__device__ __forceinline__ float min3abs(float acc, float d0, float d1) {
    float r;
    asm("v_min3_f32 %0, %1, |%2|, |%3|"
        : "=v"(r) : "v"(acc), "v"(d0), "v"(d1));
    return r;
}

// ---------------------------------------------------------------------------
// Scan kernel. Side (x-queries-vs-y-db or y-queries-vs-x-db) is chosen by
// blockIdx.y ONLY, so db / qsrc / dbn are provably wave-uniform -> the db
// reads select to s_load_dwordx8 (SGPR broadcast), leaving the inner loop
// pure VALU: per 8 db elems per query, 8 v_sub + 4 v_min3 = 1.5 VALU/visit.
// ---------------------------------------------------------------------------
__global__ __launch_bounds__(TPB) void
chamfer_scan(const float* __restrict__ x, const float* __restrict__ y,
             int n, int m, int nbx, float* __restrict__ partial) {
    const bool side_x = ((int)blockIdx.y < nbx);          // uniform branch
    const float* __restrict__ qsrc = side_x ? x : y;
    const float* __restrict__ db   = side_x ? y : x;      // uniform pointer
    const int qn  = side_x ? n : m;
    const int dbn = side_x ? m : n;
    const int by  = side_x ? (int)blockIdx.y : (int)blockIdx.y - nbx;

    const int qoff = (by * TPB + (int)threadIdx.x) * Q;   // within side
    if (qoff >= qn) return;
    const int total = n + m;
    const int gbase = side_x ? qoff : n + qoff;           // global query idx

    float qv[Q];
    if (qoff + Q <= qn) {
#pragma unroll
        for (int k = 0; k < Q; ++k) qv[k] = qsrc[qoff + k];
    } else {
#pragma unroll
        for (int k = 0; k < Q; ++k)
            qv[k] = qsrc[min(qoff + k, qn - 1)];
    }

    const int chunk_len = (dbn + CHUNKS - 1) / CHUNKS;
    const int start = (int)blockIdx.x * chunk_len;
    const int end = min(start + chunk_len, dbn);

    float acc[Q];
#pragma unroll
    for (int k = 0; k < Q; ++k) acc[k] = FLT_MAX;

    int j = start;
#pragma unroll 4
    for (; j + 8 <= end; j += 8) {
        // Uniform index + uniform pointer -> scalar loads (SGPR broadcast).
        const float v0 = db[j + 0], v1 = db[j + 1];
        const float v2 = db[j + 2], v3 = db[j + 3];
        const float v4 = db[j + 4], v5 = db[j + 5];
        const float v6 = db[j + 6], v7 = db[j + 7];
#pragma unroll
        for (int k = 0; k < Q; ++k) {
            const float q = qv[k];
            float a = acc[k];
            a = min3abs(a, v0 - q, v1 - q);
            a = min3abs(a, v2 - q, v3 - q);
            a = min3abs(a, v4 - q, v5 - q);
            a = min3abs(a, v6 - q, v7 - q);
            acc[k] = a;
        }
    }
    for (; j < end; ++j) {
        const float v = db[j];
#pragma unroll
        for (int k = 0; k < Q; ++k) acc[k] = fminf(acc[k], fabsf(qv[k] - v));
    }

    float* __restrict__ dst = partial + (size_t)blockIdx.x * total + gbase;
    if (qoff + Q <= qn) {
#pragma unroll
        for (int k = 0; k < Q; ++k) dst[k] = acc[k];
    } else {
#pragma unroll
        for (int k = 0; k < Q; ++k)
            if (qoff + k < qn) dst[k] = acc[k];
    }
}

// Reduce 1: one block per RBLK contiguous queries. 256 threads =
// RBLK queries x 2 chunk-halves; lanes read consecutive queries (coalesced).
__global__ __launch_bounds__(TPB) void
chamfer_reduce1(const float* __restrict__ vals, int n, int m,
                double* __restrict__ bsums) {
    const int total = n + m;
    const int lq = threadIdx.x & (RBLK - 1);   // query within block
    const int h = threadIdx.x >> 7;            // chunk half (0/1)
    const int q = blockIdx.x * RBLK + lq;

    float mv = FLT_MAX;
    if (q < total) {
        const int c0 = h * (CHUNKS / 2), c1 = c0 + CHUNKS / 2;
        for (int c = c0; c < c1; ++c)
            mv = fminf(mv, vals[(size_t)c * total + q]);
    }
    __shared__ float half1[RBLK];
    if (h == 1) half1[lq] = mv;
    __syncthreads();

    double sx = 0.0, sy = 0.0;
    if (h == 0 && q < total) {
        const float best = fminf(mv, half1[lq]);
        if (q < n) sx = (double)best; else sy = (double)best;
    }
    for (int off = 32; off > 0; off >>= 1) {
        sx += __shfl_down(sx, off);
        sy += __shfl_down(sy, off);
    }
    __shared__ double wsx[2], wsy[2];
    if (h == 0 && (threadIdx.x & 63) == 0) {
        wsx[threadIdx.x >> 6] = sx;
        wsy[threadIdx.x >> 6] = sy;
    }
    __syncthreads();
    if (threadIdx.x == 0) {
        bsums[2 * blockIdx.x]     = wsx[0] + wsx[1];
        bsums[2 * blockIdx.x + 1] = wsy[0] + wsy[1];
    }
}

// Reduce 2: fold nb block sums -> scalar loss.
__global__ __launch_bounds__(TPB) void
chamfer_reduce2(const double* __restrict__ bsums, int nb,
                int n, int m, float* __restrict__ out) {
    double sx = 0.0, sy = 0.0;
    for (int i = threadIdx.x; i < nb; i += blockDim.x) {
        sx += bsums[2 * i];
        sy += bsums[2 * i + 1];
    }
    for (int off = 32; off > 0; off >>= 1) {
        sx += __shfl_down(sx, off);
        sy += __shfl_down(sy, off);
    }
    __shared__ double lsx[4], lsy[4];
    const int wave = threadIdx.x >> 6;
    if ((threadIdx.x & 63) == 0) { lsx[wave] = sx; lsy[wave] = sy; }
    __syncthreads();
    if (threadIdx.x == 0) {
        double tx = 0.0, ty = 0.0;
        for (int w = 0; w < (int)(blockDim.x >> 6); ++w) { tx += lsx[w]; ty += lsy[w]; }
        const double a = (double)ALPHA;
        out[0] = (float)(a * tx / (double)n + (1.0 - a) * ty / (double)m);
    }
}

extern "C" void kernel_launch(void* const* d_in, const int* in_sizes, int n_in,
                              void* d_out, int out_size, void* d_ws, size_t ws_size,
                              hipStream_t stream) {
    const float* x = (const float*)d_in[0];
    const float* y = (const float*)d_in[1];
    const int n = in_sizes[0];
    const int m = in_sizes[1];
    float* out = (float*)d_out;
    const int total = n + m;

    const int qpb = TPB * Q;                       // queries per block
    const int nbx = (n + qpb - 1) / qpb;
    const int nby = (m + qpb - 1) / qpb;
    const dim3 grid1(CHUNKS, nbx + nby);
    const int nb1 = (total + RBLK - 1) / RBLK;

    const size_t partial_bytes = (size_t)CHUNKS * total * sizeof(float);
    const size_t partial_aligned = (partial_bytes + 255) & ~(size_t)255;

    float* partial = (float*)d_ws;
    double* bsums = (double*)((char*)d_ws + partial_aligned);

    chamfer_scan<<<grid1, TPB, 0, stream>>>(x, y, n, m, nbx, partial);
    chamfer_reduce1<<<nb1, TPB, 0, stream>>>(partial, n, m, bsums);
    chamfer_reduce2<<<1, TPB, 0, stream>>>(bsums, nb1, n, m, out);
}

// Round 6
// 81.680 us; speedup vs baseline: 1.1290x; 1.0289x over previous
//
#include <hip/hip_runtime.h>
#include <cfloat>

#define TPB 256
#define Q 8          // queries per thread (register tile)
#define CHUNKS 64    // db chunks (parallelism dimension)
#define LTILE 2048   // LDS tile capacity (floats)
#define RBLK 128     // queries per reduce1 block
#define ALPHA 0.5f

// acc = min(acc, |d0|, |d1|) in ONE VALU instruction (IEEE mode blocks the
// compiler's own min3+abs fusion).
__device__ __forceinline__ float min3abs(float acc, float d0, float d1) {
    float r;
    asm("v_min3_f32 %0, %1, |%2|, |%3|"
        : "=v"(r) : "v"(acc), "v"(d0), "v"(d1));
    return r;
}

// ---------------------------------------------------------------------------
// Scan kernel, LDS-broadcast edition. The db chunk is staged into LDS by a
// coalesced cooperative load; the inner loop has every lane read the SAME
// LDS address -> hardware broadcast (no bank conflicts, no global latency).
// Per 8 db elems per wave: 2x ds_read_b128 (24 DS-cyc) vs Q*12*2 = 192
// VALU-cyc -> DS pipe 50% utilized, VALU is the binding pipe (10.2 us floor).
// ---------------------------------------------------------------------------
__global__ __launch_bounds__(TPB) void
chamfer_scan(const float* __restrict__ x, const float* __restrict__ y,
             int n, int m, int nbx, float* __restrict__ partial) {
    __shared__ float s_db[LTILE] __attribute__((aligned(16)));

    const bool side_x = ((int)blockIdx.y < nbx);          // uniform branch
    const float* __restrict__ qsrc = side_x ? x : y;
    const float* __restrict__ db   = side_x ? y : x;
    const int qn  = side_x ? n : m;
    const int dbn = side_x ? m : n;
    const int by  = side_x ? (int)blockIdx.y : (int)blockIdx.y - nbx;

    const int qoff = (by * TPB + (int)threadIdx.x) * Q;   // within side
    const int total = n + m;
    const int gbase = side_x ? qoff : n + qoff;           // global query idx
    const bool live = (qoff < qn);

    float qv[Q];
#pragma unroll
    for (int k = 0; k < Q; ++k)
        qv[k] = live ? qsrc[min(qoff + k, qn - 1)] : 0.0f;

    const int chunk_len = (dbn + CHUNKS - 1) / CHUNKS;
    const int start = (int)blockIdx.x * chunk_len;
    const int end = min(start + chunk_len, dbn);

    float acc[Q];
#pragma unroll
    for (int k = 0; k < Q; ++k) acc[k] = FLT_MAX;

    for (int ts = start; ts < end; ts += LTILE) {
        const int tlen = min(LTILE, end - ts);
        // Coalesced cooperative stage (even dead-query threads help load).
        for (int i = threadIdx.x; i < tlen; i += TPB) s_db[i] = db[ts + i];
        __syncthreads();

        const float4* __restrict__ s4 = (const float4*)s_db;
        const int ng = tlen >> 3;
        for (int g = 0; g < ng; ++g) {
            const float4 a = s4[2 * g];       // ds_read_b128, broadcast
            const float4 b = s4[2 * g + 1];   // ds_read_b128, broadcast
#pragma unroll
            for (int k = 0; k < Q; ++k) {
                const float q = qv[k];
                float acc_k = acc[k];
                acc_k = min3abs(acc_k, a.x - q, a.y - q);
                acc_k = min3abs(acc_k, a.z - q, a.w - q);
                acc_k = min3abs(acc_k, b.x - q, b.y - q);
                acc_k = min3abs(acc_k, b.z - q, b.w - q);
                acc[k] = acc_k;
            }
        }
        for (int j = ng << 3; j < tlen; ++j) {
            const float v = s_db[j];
#pragma unroll
            for (int k = 0; k < Q; ++k) acc[k] = fminf(acc[k], fabsf(qv[k] - v));
        }
        __syncthreads();
    }

    if (!live) return;
    float* __restrict__ dst = partial + (size_t)blockIdx.x * total + gbase;
    if (qoff + Q <= qn) {
#pragma unroll
        for (int k = 0; k < Q; ++k) dst[k] = acc[k];
    } else {
#pragma unroll
        for (int k = 0; k < Q; ++k)
            if (qoff + k < qn) dst[k] = acc[k];
    }
}

// Reduce 1: one block per RBLK contiguous queries. 256 threads =
// RBLK queries x 2 chunk-halves; lanes read consecutive queries (coalesced).
__global__ __launch_bounds__(TPB) void
chamfer_reduce1(const float* __restrict__ vals, int n, int m,
                double* __restrict__ bsums) {
    const int total = n + m;
    const int lq = threadIdx.x & (RBLK - 1);   // query within block
    const int h = threadIdx.x >> 7;            // chunk half (0/1)
    const int q = blockIdx.x * RBLK + lq;

    float mv = FLT_MAX;
    if (q < total) {
        const int c0 = h * (CHUNKS / 2), c1 = c0 + CHUNKS / 2;
        for (int c = c0; c < c1; ++c)
            mv = fminf(mv, vals[(size_t)c * total + q]);
    }
    __shared__ float half1[RBLK];
    if (h == 1) half1[lq] = mv;
    __syncthreads();

    double sx = 0.0, sy = 0.0;
    if (h == 0 && q < total) {
        const float best = fminf(mv, half1[lq]);
        if (q < n) sx = (double)best; else sy = (double)best;
    }
    for (int off = 32; off > 0; off >>= 1) {
        sx += __shfl_down(sx, off);
        sy += __shfl_down(sy, off);
    }
    __shared__ double wsx[2], wsy[2];
    if (h == 0 && (threadIdx.x & 63) == 0) {
        wsx[threadIdx.x >> 6] = sx;
        wsy[threadIdx.x >> 6] = sy;
    }
    __syncthreads();
    if (threadIdx.x == 0) {
        bsums[2 * blockIdx.x]     = wsx[0] + wsx[1];
        bsums[2 * blockIdx.x + 1] = wsy[0] + wsy[1];
    }
}

// Reduce 2: fold nb block sums -> scalar loss.
__global__ __launch_bounds__(TPB) void
chamfer_reduce2(const double* __restrict__ bsums, int nb,
                int n, int m, float* __restrict__ out) {
    double sx = 0.0, sy = 0.0;
    for (int i = threadIdx.x; i < nb; i += blockDim.x) {
        sx += bsums[2 * i];
        sy += bsums[2 * i + 1];
    }
    for (int off = 32; off > 0; off >>= 1) {
        sx += __shfl_down(sx, off);
        sy += __shfl_down(sy, off);
    }
    __shared__ double lsx[4], lsy[4];
    const int wave = threadIdx.x >> 6;
    if ((threadIdx.x & 63) == 0) { lsx[wave] = sx; lsy[wave] = sy; }
    __syncthreads();
    if (threadIdx.x == 0) {
        double tx = 0.0, ty = 0.0;
        for (int w = 0; w < (int)(blockDim.x >> 6); ++w) { tx += lsx[w]; ty += lsy[w]; }
        const double a = (double)ALPHA;
        out[0] = (float)(a * tx / (double)n + (1.0 - a) * ty / (double)m);
    }
}

extern "C" void kernel_launch(void* const* d_in, const int* in_sizes, int n_in,
                              void* d_out, int out_size, void* d_ws, size_t ws_size,
                              hipStream_t stream) {
    const float* x = (const float*)d_in[0];
    const float* y = (const float*)d_in[1];
    const int n = in_sizes[0];
    const int m = in_sizes[1];
    float* out = (float*)d_out;
    const int total = n + m;

    const int qpb = TPB * Q;                       // queries per block
    const int nbx = (n + qpb - 1) / qpb;
    const int nby = (m + qpb - 1) / qpb;
    const dim3 grid1(CHUNKS, nbx + nby);
    const int nb1 = (total + RBLK - 1) / RBLK;

    const size_t partial_bytes = (size_t)CHUNKS * total * sizeof(float);
    const size_t partial_aligned = (partial_bytes + 255) & ~(size_t)255;

    float* partial = (float*)d_ws;
    double* bsums = (double*)((char*)d_ws + partial_aligned);

    chamfer_scan<<<grid1, TPB, 0, stream>>>(x, y, n, m, nbx, partial);
    chamfer_reduce1<<<nb1, TPB, 0, stream>>>(partial, n, m, bsums);
    chamfer_reduce2<<<1, TPB, 0, stream>>>(bsums, nb1, n, m, out);
}